// Round 1
// baseline (855.245 us; speedup 1.0000x reference)
//
#include <hip/hip_runtime.h>
#include <math.h>

#define AS1 __attribute__((address_space(1)))
#define AS3 __attribute__((address_space(3)))

typedef unsigned short u16;
typedef short bf16x8 __attribute__((ext_vector_type(8)));
typedef float f32x4 __attribute__((ext_vector_type(4)));

static constexpr int BB = 64, T = 256, C = 1024, H = 16, HD = 64;
static constexpr int M = BB * T;          // 16384 token rows
static constexpr float EPSF = 1e-5f;

// ---- workspace layout (bytes) ----
static constexpr size_t W8_OFF   = 0;                    // 4 x 1M u16  = 8 MiB (ternary weights, bf16 bits)
static constexpr size_t XQ8_OFF  = 8ull  << 20;          // 16M u16    = 32 MiB (int8-valued bf16; reused for yq)
static constexpr size_t RSX_OFF  = 40ull << 20;          // 16384 f32
static constexpr size_t RSY_OFF  = (40ull << 20) + (64 << 10);
static constexpr size_t WSUM_OFF = (40ull << 20) + (128 << 10);   // 4 f64
static constexpr size_t WPART_OFF= WSUM_OFF + 64;                 // 256 f64
static constexpr size_t QB_OFF   = 41ull  << 20;         // 64 MiB f32
static constexpr size_t KB_OFF   = 105ull << 20;         // 64 MiB f32
static constexpr size_t VB_OFF   = 169ull << 20;         // 64 MiB f32  (total 233 MiB)

// float (exact small integer) -> bf16 bits: low 16 bits of the f32 encoding are
// zero for integers in [-128,127] and for {-1,0,1}, so truncation is exact.
__device__ __forceinline__ u16 f32i_to_bf16(float f) {
    return (u16)(__float_as_uint(f) >> 16);
}

// ---------------- weight |w| sum, stage 1 (deterministic, f64) ----------------
__global__ __launch_bounds__(256) void wsum1_kernel(const float* __restrict__ Wq,
    const float* __restrict__ Wk, const float* __restrict__ Wv,
    const float* __restrict__ Wp, double* __restrict__ wpart)
{
    const int mat = blockIdx.x >> 6;
    const float* W = (mat == 0) ? Wq : (mat == 1) ? Wk : (mat == 2) ? Wv : Wp;
    const int t = threadIdx.x;
    const int base = (blockIdx.x & 63) * 256 + t;
    double s = 0.0;
    for (int i = 0; i < 64; ++i) s += (double)fabsf(W[base + (i << 14)]);
    #pragma unroll
    for (int off = 32; off >= 1; off >>= 1) s += __shfl_down(s, off);
    __shared__ double red[4];
    if ((t & 63) == 0) red[t >> 6] = s;
    __syncthreads();
    if (t == 0) wpart[blockIdx.x] = red[0] + red[1] + red[2] + red[3];
}

// ---------------- weight |w| sum, stage 2 ----------------
__global__ __launch_bounds__(256) void wsum2_kernel(const double* __restrict__ wpart,
                                                    double* __restrict__ wsum)
{
    const int t = threadIdx.x;
    double s = wpart[t];
    #pragma unroll
    for (int off = 32; off >= 1; off >>= 1) s += __shfl_down(s, off);
    if ((t & 63) == 0) wsum[t >> 6] = s;
}

// ---------------- ternary weight quantization ----------------
__global__ __launch_bounds__(256) void wquant_kernel(const float* __restrict__ Wq,
    const float* __restrict__ Wk, const float* __restrict__ Wv,
    const float* __restrict__ Wp, const double* __restrict__ wsum,
    u16* __restrict__ w8)
{
    const int mat = blockIdx.x >> 10;
    const float* W = (mat == 0) ? Wq : (mat == 1) ? Wk : (mat == 2) ? Wv : Wp;
    const float mean = (float)(wsum[mat] * (1.0 / 1048576.0));
    const float s = 1.0f / fmaxf(mean, EPSF);
    const int idx = (blockIdx.x & 1023) * 256 + threadIdx.x;   // float4 index
    float4 w = ((const float4*)W)[idx];
    float qx = fminf(fmaxf(rintf(w.x * s), -1.f), 1.f);
    float qy = fminf(fmaxf(rintf(w.y * s), -1.f), 1.f);
    float qz = fminf(fmaxf(rintf(w.z * s), -1.f), 1.f);
    float qw = fminf(fmaxf(rintf(w.w * s), -1.f), 1.f);
    ushort4 o;
    o.x = f32i_to_bf16(qx); o.y = f32i_to_bf16(qy);
    o.z = f32i_to_bf16(qz); o.w = f32i_to_bf16(qw);
    ((ushort4*)(w8 + (size_t)mat * 1048576))[idx] = o;
}

// ---------------- per-token activation quantization ----------------
__global__ __launch_bounds__(256) void actquant_kernel(const float* __restrict__ x,
    u16* __restrict__ xq, float* __restrict__ rs)
{
    const int row = blockIdx.x;
    const int t = threadIdx.x;
    float4 v = ((const float4*)(x + (size_t)row * C))[t];
    float m = fmaxf(fmaxf(fabsf(v.x), fabsf(v.y)), fmaxf(fabsf(v.z), fabsf(v.w)));
    #pragma unroll
    for (int off = 32; off >= 1; off >>= 1) m = fmaxf(m, __shfl_down(m, off));
    __shared__ float red[4];
    if ((t & 63) == 0) red[t >> 6] = m;
    __syncthreads();
    float mm = fmaxf(fmaxf(red[0], red[1]), fmaxf(red[2], red[3]));
    mm = fmaxf(mm, EPSF);
    const float s = 127.0f / mm;
    if (t == 0) rs[row] = mm / 127.0f;
    float qx = fminf(fmaxf(rintf(v.x * s), -128.f), 127.f);
    float qy = fminf(fmaxf(rintf(v.y * s), -128.f), 127.f);
    float qz = fminf(fmaxf(rintf(v.z * s), -128.f), 127.f);
    float qw = fminf(fmaxf(rintf(v.w * s), -128.f), 127.f);
    ushort4 o;
    o.x = f32i_to_bf16(qx); o.y = f32i_to_bf16(qy);
    o.z = f32i_to_bf16(qz); o.w = f32i_to_bf16(qw);
    ((ushort4*)(xq + (size_t)row * C))[t] = o;
}

// ---------------- bf16 MFMA GEMM: out[M,1024] = A[M,1024] x W[1024,1024]^T ----------------
// A, W hold exact small integers encoded as bf16. Epilogue: * rs_row[m] * clip(mean|w|) (+ bias).
__global__ __launch_bounds__(256) void gemm_kernel(const u16* __restrict__ A,
    const u16* __restrict__ Bw, const float* __restrict__ rs_row,
    const double* __restrict__ wsum, float* __restrict__ out,
    const float* __restrict__ bias)
{
    constexpr int K = 1024, N = 1024;
    __shared__ __align__(16) u16 Asm[128 * 32];
    __shared__ __align__(16) u16 Bsm[128 * 32];

    const int t = threadIdx.x;
    const int m0 = blockIdx.y * 128;
    const int n0 = blockIdx.x * 128;
    const int lane = t & 63, wave = t >> 6;
    const int wm = wave >> 1, wn = wave & 1;      // 2x2 wave grid, 64x64 each
    const int mr = lane & 15, quad = lane >> 4;

    f32x4 zero = {0.f, 0.f, 0.f, 0.f};
    f32x4 acc[4][4];
    #pragma unroll
    for (int i = 0; i < 4; ++i)
        #pragma unroll
        for (int j = 0; j < 4; ++j) acc[i][j] = zero;

    // staging: 512 chunks of 16B per tile; chunk c -> row c>>2, k-offset (c&3)*8
    const int c0 = t, c1 = t + 256;
    const int ar0 = c0 >> 2, ak0 = (c0 & 3) * 8;
    const int ar1 = c1 >> 2, ak1 = (c1 & 3) * 8;
    const u16* a0 = A  + (size_t)(m0 + ar0) * K + ak0;
    const u16* a1 = A  + (size_t)(m0 + ar1) * K + ak1;
    const u16* b0 = Bw + (size_t)(n0 + ar0) * K + ak0;
    const u16* b1 = Bw + (size_t)(n0 + ar1) * K + ak1;

    for (int k0 = 0; k0 < K; k0 += 32) {
        __builtin_amdgcn_global_load_lds((const AS1 void*)(a0 + k0), (AS3 void*)&Asm[c0 * 8], 16, 0, 0);
        __builtin_amdgcn_global_load_lds((const AS1 void*)(a1 + k0), (AS3 void*)&Asm[c1 * 8], 16, 0, 0);
        __builtin_amdgcn_global_load_lds((const AS1 void*)(b0 + k0), (AS3 void*)&Bsm[c0 * 8], 16, 0, 0);
        __builtin_amdgcn_global_load_lds((const AS1 void*)(b1 + k0), (AS3 void*)&Bsm[c1 * 8], 16, 0, 0);
        __syncthreads();
        bf16x8 af[4], bf[4];
        #pragma unroll
        for (int i = 0; i < 4; ++i)
            af[i] = *(const bf16x8*)&Asm[(wm * 64 + i * 16 + mr) * 32 + quad * 8];
        #pragma unroll
        for (int j = 0; j < 4; ++j)
            bf[j] = *(const bf16x8*)&Bsm[(wn * 64 + j * 16 + mr) * 32 + quad * 8];
        #pragma unroll
        for (int i = 0; i < 4; ++i)
            #pragma unroll
            for (int j = 0; j < 4; ++j)
                acc[i][j] = __builtin_amdgcn_mfma_f32_16x16x32_bf16(af[i], bf[j], acc[i][j], 0, 0, 0);
        __syncthreads();
    }

    const float wsc = fmaxf((float)(wsum[0] * (1.0 / 1048576.0)), EPSF);
    #pragma unroll
    for (int i = 0; i < 4; ++i) {
        const int gr0 = m0 + wm * 64 + i * 16 + quad * 4;
        #pragma unroll
        for (int r = 0; r < 4; ++r) {
            const int grow = gr0 + r;
            const float sc = rs_row[grow] * wsc;
            #pragma unroll
            for (int j = 0; j < 4; ++j) {
                const int gcol = n0 + wn * 64 + j * 16 + mr;
                float vv = acc[i][j][r] * sc;
                if (bias) vv += bias[gcol];
                out[(size_t)grow * N + gcol] = vv;
            }
        }
    }
}

// ---------------- causal attention, one block per (b,h), thread = query row ----------------
__global__ __launch_bounds__(256, 2) void attn_kernel(const float* __restrict__ q,
    const float* __restrict__ k, const float* __restrict__ v, float* __restrict__ y)
{
    const int bh = blockIdx.x;
    const int b = bh >> 4, h = bh & 15;
    const size_t base = (size_t)b * T * C + (size_t)h * HD;
    const int t = threadIdx.x;

    float qr[HD];
    {
        const float* qrow = q + base + (size_t)t * C;
        #pragma unroll
        for (int c4 = 0; c4 < HD / 4; ++c4) {
            float4 tv = *(const float4*)(qrow + c4 * 4);
            qr[c4 * 4 + 0] = tv.x * 0.125f;   // fold 1/sqrt(64), exact pow2
            qr[c4 * 4 + 1] = tv.y * 0.125f;
            qr[c4 * 4 + 2] = tv.z * 0.125f;
            qr[c4 * 4 + 3] = tv.w * 0.125f;
        }
    }

    __shared__ __align__(16) float Kt[64 * HD];
    __shared__ __align__(16) float Vt[64 * HD];

    float mrun = -INFINITY, lrun = 0.f;
    float acc[HD];
    #pragma unroll
    for (int d = 0; d < HD; ++d) acc[d] = 0.f;

    for (int tile = 0; tile < 4; ++tile) {
        #pragma unroll
        for (int i = 0; i < 4; ++i) {
            int f4 = t + 256 * i;                     // 1024 float4 slots
            int row = f4 >> 4, cc = f4 & 15;
            const float* ks = k + base + (size_t)(tile * 64 + row) * C + cc * 4;
            const float* vs = v + base + (size_t)(tile * 64 + row) * C + cc * 4;
            ((float4*)Kt)[f4] = *(const float4*)ks;
            ((float4*)Vt)[f4] = *(const float4*)vs;
        }
        __syncthreads();
        const int jmax = min(64, t - tile * 64 + 1);
        for (int j = 0; j < jmax; ++j) {
            float s = 0.f;
            #pragma unroll
            for (int c4 = 0; c4 < HD / 4; ++c4) {
                float4 kv = ((const float4*)Kt)[j * (HD / 4) + c4];
                s += qr[c4*4+0]*kv.x + qr[c4*4+1]*kv.y + qr[c4*4+2]*kv.z + qr[c4*4+3]*kv.w;
            }
            float nm = fmaxf(mrun, s);
            float corr = __expf(mrun - nm);     // exp(-inf)=0 handles first iter
            float p = __expf(s - nm);
            lrun = lrun * corr + p;
            #pragma unroll
            for (int c4 = 0; c4 < HD / 4; ++c4) {
                float4 vv = ((const float4*)Vt)[j * (HD / 4) + c4];
                acc[c4*4+0] = acc[c4*4+0] * corr + p * vv.x;
                acc[c4*4+1] = acc[c4*4+1] * corr + p * vv.y;
                acc[c4*4+2] = acc[c4*4+2] * corr + p * vv.z;
                acc[c4*4+3] = acc[c4*4+3] * corr + p * vv.w;
            }
            mrun = nm;
        }
        __syncthreads();
    }

    const float inv = 1.0f / lrun;
    float* yrow = y + base + (size_t)t * C;
    #pragma unroll
    for (int c4 = 0; c4 < HD / 4; ++c4) {
        float4 ov;
        ov.x = acc[c4*4+0] * inv; ov.y = acc[c4*4+1] * inv;
        ov.z = acc[c4*4+2] * inv; ov.w = acc[c4*4+3] * inv;
        *(float4*)(yrow + c4 * 4) = ov;
    }
}

extern "C" void kernel_launch(void* const* d_in, const int* in_sizes, int n_in,
                              void* d_out, int out_size, void* d_ws, size_t ws_size,
                              hipStream_t stream) {
    (void)in_sizes; (void)n_in; (void)out_size; (void)ws_size;
    const float* x  = (const float*)d_in[0];
    const float* Wq = (const float*)d_in[1];
    const float* Wk = (const float*)d_in[2];
    const float* Wv = (const float*)d_in[3];
    const float* Wp = (const float*)d_in[4];
    const float* bp = (const float*)d_in[5];
    float* out = (float*)d_out;
    char* ws = (char*)d_ws;

    u16*    w8   = (u16*)(ws + W8_OFF);
    u16*    xq8  = (u16*)(ws + XQ8_OFF);     // reused as yq8 later
    float*  rsx  = (float*)(ws + RSX_OFF);
    float*  rsy  = (float*)(ws + RSY_OFF);
    double* wsum = (double*)(ws + WSUM_OFF);
    double* wpart= (double*)(ws + WPART_OFF);
    float*  qb   = (float*)(ws + QB_OFF);
    float*  kb   = (float*)(ws + KB_OFF);
    float*  vb   = (float*)(ws + VB_OFF);

    wsum1_kernel<<<256, 256, 0, stream>>>(Wq, Wk, Wv, Wp, wpart);
    wsum2_kernel<<<1, 256, 0, stream>>>(wpart, wsum);
    wquant_kernel<<<4096, 256, 0, stream>>>(Wq, Wk, Wv, Wp, wsum, w8);
    actquant_kernel<<<M, 256, 0, stream>>>(x, xq8, rsx);

    dim3 gg(1024 / 128, M / 128);
    gemm_kernel<<<gg, 256, 0, stream>>>(xq8, w8 + 0 * 1048576, rsx, wsum + 0, qb, nullptr);
    gemm_kernel<<<gg, 256, 0, stream>>>(xq8, w8 + 1 * 1048576, rsx, wsum + 1, kb, nullptr);
    gemm_kernel<<<gg, 256, 0, stream>>>(xq8, w8 + 2 * 1048576, rsx, wsum + 2, vb, nullptr);

    attn_kernel<<<BB * H, 256, 0, stream>>>(qb, kb, vb, out);   // y -> d_out (scratch)

    actquant_kernel<<<M, 256, 0, stream>>>(out, xq8, rsy);      // y -> yq8 (reuse xq8)
    gemm_kernel<<<gg, 256, 0, stream>>>(xq8, w8 + 3 * 1048576, rsy, wsum + 3, out, bp);
}

// Round 2
// 465.893 us; speedup vs baseline: 1.8357x; 1.8357x over previous
//
#include <hip/hip_runtime.h>
#include <math.h>

#define AS1 __attribute__((address_space(1)))
#define AS3 __attribute__((address_space(3)))

typedef unsigned short u16;
typedef short bf16x8 __attribute__((ext_vector_type(8)));
typedef float f32x4 __attribute__((ext_vector_type(4)));

static constexpr int BB = 64, T = 256, C = 1024, H = 16, HD = 64;
static constexpr int M = BB * T;          // 16384 token rows
static constexpr float EPSF = 1e-5f;

// ---- workspace layout (bytes) ----
static constexpr size_t W8_OFF   = 0;                    // 4 x 1M u16  = 8 MiB ternary weights (bf16 bits)
static constexpr size_t XQ8_OFF  = 8ull  << 20;          // 16M u16 = 32 MiB int8-valued bf16 (reused for yq)
static constexpr size_t RSX_OFF  = 40ull << 20;          // 16384 f32
static constexpr size_t RSY_OFF  = (40ull << 20) + (64 << 10);
static constexpr size_t WSUM_OFF = (40ull << 20) + (128 << 10);   // 4 f64
static constexpr size_t WPART_OFF= WSUM_OFF + 64;                 // 256 f64
static constexpr size_t QB_OFF   = 41ull  << 20;         // 32 MiB bf16
static constexpr size_t KB_OFF   = 73ull  << 20;         // 32 MiB bf16
static constexpr size_t VB_OFF   = 105ull << 20;         // 32 MiB bf16 (total 137 MiB)

// exact small integer f32 -> bf16 bits (low mantissa bits are zero, truncation exact)
__device__ __forceinline__ u16 f32i_to_bf16(float f) {
    return (u16)(__float_as_uint(f) >> 16);
}
// round-to-nearest-even f32 -> bf16 bits (finite inputs)
__device__ __forceinline__ u16 f2bf_rne(float f) {
    unsigned x = __float_as_uint(f);
    unsigned r = x + 0x7FFF + ((x >> 16) & 1);
    return (u16)(r >> 16);
}

// ---------------- weight |w| sum, stage 1 (deterministic, f64) ----------------
__global__ __launch_bounds__(256) void wsum1_kernel(const float* __restrict__ Wq,
    const float* __restrict__ Wk, const float* __restrict__ Wv,
    const float* __restrict__ Wp, double* __restrict__ wpart)
{
    const int mat = blockIdx.x >> 6;
    const float* W = (mat == 0) ? Wq : (mat == 1) ? Wk : (mat == 2) ? Wv : Wp;
    const int t = threadIdx.x;
    const int base = (blockIdx.x & 63) * 256 + t;
    double s = 0.0;
    for (int i = 0; i < 64; ++i) s += (double)fabsf(W[base + (i << 14)]);
    #pragma unroll
    for (int off = 32; off >= 1; off >>= 1) s += __shfl_down(s, off);
    __shared__ double red[4];
    if ((t & 63) == 0) red[t >> 6] = s;
    __syncthreads();
    if (t == 0) wpart[blockIdx.x] = red[0] + red[1] + red[2] + red[3];
}

__global__ __launch_bounds__(256) void wsum2_kernel(const double* __restrict__ wpart,
                                                    double* __restrict__ wsum)
{
    const int t = threadIdx.x;
    double s = wpart[t];
    #pragma unroll
    for (int off = 32; off >= 1; off >>= 1) s += __shfl_down(s, off);
    if ((t & 63) == 0) wsum[t >> 6] = s;
}

// ---------------- ternary weight quantization ----------------
__global__ __launch_bounds__(256) void wquant_kernel(const float* __restrict__ Wq,
    const float* __restrict__ Wk, const float* __restrict__ Wv,
    const float* __restrict__ Wp, const double* __restrict__ wsum,
    u16* __restrict__ w8)
{
    const int mat = blockIdx.x >> 10;
    const float* W = (mat == 0) ? Wq : (mat == 1) ? Wk : (mat == 2) ? Wv : Wp;
    const float mean = (float)(wsum[mat] * (1.0 / 1048576.0));
    const float s = 1.0f / fmaxf(mean, EPSF);
    const int idx = (blockIdx.x & 1023) * 256 + threadIdx.x;   // float4 index
    float4 w = ((const float4*)W)[idx];
    ushort4 o;
    o.x = f32i_to_bf16(fminf(fmaxf(rintf(w.x * s), -1.f), 1.f));
    o.y = f32i_to_bf16(fminf(fmaxf(rintf(w.y * s), -1.f), 1.f));
    o.z = f32i_to_bf16(fminf(fmaxf(rintf(w.z * s), -1.f), 1.f));
    o.w = f32i_to_bf16(fminf(fmaxf(rintf(w.w * s), -1.f), 1.f));
    ((ushort4*)(w8 + (size_t)mat * 1048576))[idx] = o;
}

// ---------------- per-token activation quantization ----------------
__global__ __launch_bounds__(256) void actquant_kernel(const float* __restrict__ x,
    u16* __restrict__ xq, float* __restrict__ rs)
{
    const int row = blockIdx.x;
    const int t = threadIdx.x;
    float4 v = ((const float4*)(x + (size_t)row * C))[t];
    float m = fmaxf(fmaxf(fabsf(v.x), fabsf(v.y)), fmaxf(fabsf(v.z), fabsf(v.w)));
    #pragma unroll
    for (int off = 32; off >= 1; off >>= 1) m = fmaxf(m, __shfl_down(m, off));
    __shared__ float red[4];
    if ((t & 63) == 0) red[t >> 6] = m;
    __syncthreads();
    float mm = fmaxf(fmaxf(red[0], red[1]), fmaxf(red[2], red[3]));
    mm = fmaxf(mm, EPSF);
    const float s = 127.0f / mm;
    if (t == 0) rs[row] = mm / 127.0f;
    ushort4 o;
    o.x = f32i_to_bf16(fminf(fmaxf(rintf(v.x * s), -128.f), 127.f));
    o.y = f32i_to_bf16(fminf(fmaxf(rintf(v.y * s), -128.f), 127.f));
    o.z = f32i_to_bf16(fminf(fmaxf(rintf(v.z * s), -128.f), 127.f));
    o.w = f32i_to_bf16(fminf(fmaxf(rintf(v.w * s), -128.f), 127.f));
    ((ushort4*)(xq + (size_t)row * C))[t] = o;
}

// ---------------- bf16 MFMA GEMM: out[M,1024] = A[M,1024] x W[1024,1024]^T ----------------
// Epilogue scale = rs_row[m] * clip(mean|w|) * mult; BF16OUT writes bf16, else f32 + bias.
template<bool BF16OUT>
__global__ __launch_bounds__(256) void gemm_kernel(const u16* __restrict__ A,
    const u16* __restrict__ Bw, const float* __restrict__ rs_row,
    const double* __restrict__ wsum_p, void* __restrict__ outp,
    const float* __restrict__ bias, float mult)
{
    constexpr int K = 1024, N = 1024;
    __shared__ __align__(16) u16 Asm[128 * 32];
    __shared__ __align__(16) u16 Bsm[128 * 32];

    const int t = threadIdx.x;
    const int m0 = blockIdx.y * 128;
    const int n0 = blockIdx.x * 128;
    const int lane = t & 63, wave = t >> 6;
    const int wm = wave >> 1, wn = wave & 1;      // 2x2 wave grid, 64x64 each
    const int mr = lane & 15, quad = lane >> 4;

    f32x4 zero = {0.f, 0.f, 0.f, 0.f};
    f32x4 acc[4][4];
    #pragma unroll
    for (int i = 0; i < 4; ++i)
        #pragma unroll
        for (int j = 0; j < 4; ++j) acc[i][j] = zero;

    const int c0 = t, c1 = t + 256;
    const int ar0 = c0 >> 2, ak0 = (c0 & 3) * 8;
    const int ar1 = c1 >> 2, ak1 = (c1 & 3) * 8;
    const u16* a0 = A  + (size_t)(m0 + ar0) * K + ak0;
    const u16* a1 = A  + (size_t)(m0 + ar1) * K + ak1;
    const u16* b0 = Bw + (size_t)(n0 + ar0) * K + ak0;
    const u16* b1 = Bw + (size_t)(n0 + ar1) * K + ak1;

    for (int k0 = 0; k0 < K; k0 += 32) {
        __builtin_amdgcn_global_load_lds((const AS1 void*)(a0 + k0), (AS3 void*)&Asm[c0 * 8], 16, 0, 0);
        __builtin_amdgcn_global_load_lds((const AS1 void*)(a1 + k0), (AS3 void*)&Asm[c1 * 8], 16, 0, 0);
        __builtin_amdgcn_global_load_lds((const AS1 void*)(b0 + k0), (AS3 void*)&Bsm[c0 * 8], 16, 0, 0);
        __builtin_amdgcn_global_load_lds((const AS1 void*)(b1 + k0), (AS3 void*)&Bsm[c1 * 8], 16, 0, 0);
        __syncthreads();
        bf16x8 af[4], bf[4];
        #pragma unroll
        for (int i = 0; i < 4; ++i)
            af[i] = *(const bf16x8*)&Asm[(wm * 64 + i * 16 + mr) * 32 + quad * 8];
        #pragma unroll
        for (int j = 0; j < 4; ++j)
            bf[j] = *(const bf16x8*)&Bsm[(wn * 64 + j * 16 + mr) * 32 + quad * 8];
        #pragma unroll
        for (int i = 0; i < 4; ++i)
            #pragma unroll
            for (int j = 0; j < 4; ++j)
                acc[i][j] = __builtin_amdgcn_mfma_f32_16x16x32_bf16(af[i], bf[j], acc[i][j], 0, 0, 0);
        __syncthreads();
    }

    const float wsc = fmaxf((float)(wsum_p[0] * (1.0 / 1048576.0)), EPSF) * mult;
    #pragma unroll
    for (int i = 0; i < 4; ++i) {
        const int gr0 = m0 + wm * 64 + i * 16 + quad * 4;
        #pragma unroll
        for (int r = 0; r < 4; ++r) {
            const int grow = gr0 + r;
            const float sc = rs_row[grow] * wsc;
            #pragma unroll
            for (int j = 0; j < 4; ++j) {
                const int gcol = n0 + wn * 64 + j * 16 + mr;
                float vv = acc[i][j][r] * sc;
                if (BF16OUT) {
                    ((u16*)outp)[(size_t)grow * N + gcol] = f2bf_rne(vv);
                } else {
                    ((float*)outp)[(size_t)grow * N + gcol] = vv + bias[gcol];
                }
            }
        }
    }
}

// ---------------- MFMA flash attention ----------------
// block = (b, h, qtile of 64 rows); 4 waves x 16 q-rows. Full S row in regs
// (exact softmax, no online rescale). Causal at 16-tile granularity + diagonal
// mask. V staged transposed in LDS (B-operand needs d-major/j-contiguous);
// P goes C-layout -> LDS -> A-layout per 32-j chunk (double-buffered).
__global__ __launch_bounds__(256) void attn_kernel(const u16* __restrict__ qb,
    const u16* __restrict__ kb, const u16* __restrict__ vb, float* __restrict__ y)
{
    __shared__ __align__(16) u16 Vsm[64 * 264];      // V^T [d][j], stride 264 (pad 8)
    __shared__ __align__(16) u16 Psm[4][2][16 * 40]; // per-wave P chunk, dbuf, stride 40

    const int t = threadIdx.x;
    const int qt = 3 - (int)(blockIdx.x >> 10);      // heavy qtiles dispatch first
    const int bh = blockIdx.x & 1023;
    const int b = bh >> 4, h = bh & 15;
    const int w = t >> 6, lane = t & 63;
    const int cl = lane & 15, quad = lane >> 4;
    const size_t gb = (size_t)(b * T) * 1024 + h * 64;

    const int jn = (qt + 1) * 64;                    // K/V rows this block needs

    // --- stage V transposed: Vsm[d][j] ---
    {
        const int j_in = t & 63;
        const int d0 = (t >> 6) * 16;
        for (int jg = 0; jg < jn; jg += 64) {
            const u16* vr = vb + gb + (size_t)(jg + j_in) * 1024 + d0;
            bf16x8 v0 = *(const bf16x8*)vr;
            bf16x8 v1 = *(const bf16x8*)(vr + 8);
            #pragma unroll
            for (int i = 0; i < 8; ++i) {
                Vsm[(d0 + i) * 264 + jg + j_in]     = (u16)v0[i];
                Vsm[(d0 + 8 + i) * 264 + jg + j_in] = (u16)v1[i];
            }
        }
    }
    __syncthreads();

    const int qrow = qt * 64 + w * 16;               // wave's q base within T
    const int jtiles = (qrow >> 4) + 1;              // causal: tiles 0..jtiles-1

    const u16* qrp = qb + gb + (size_t)(qrow + cl) * 1024 + quad * 8;
    bf16x8 qf0 = *(const bf16x8*)qrp;
    bf16x8 qf1 = *(const bf16x8*)(qrp + 32);

    f32x4 S[16];
    #pragma unroll
    for (int i = 0; i < 16; ++i) S[i] = (f32x4){0.f, 0.f, 0.f, 0.f};

    // --- S = Q K^T (K frags straight from global; L2-resident, reused 16x) ---
    const u16* krp = kb + gb + (size_t)cl * 1024 + quad * 8;
    #pragma unroll
    for (int jt = 0; jt < 16; ++jt) {
        if (jt < jtiles) {
            const u16* kp = krp + (size_t)(jt * 16) * 1024;
            bf16x8 kf0 = *(const bf16x8*)kp;
            bf16x8 kf1 = *(const bf16x8*)(kp + 32);
            S[jt] = __builtin_amdgcn_mfma_f32_16x16x32_bf16(qf0, kf0, S[jt], 0, 0, 0);
            S[jt] = __builtin_amdgcn_mfma_f32_16x16x32_bf16(qf1, kf1, S[jt], 0, 0, 0);
            if (jt == jtiles - 1) {                  // diagonal tile mask: j > q
                #pragma unroll
                for (int r = 0; r < 4; ++r)
                    if (cl > quad * 4 + r) S[jt][r] = -INFINITY;
            }
        }
    }

    // --- exact softmax over the full row (reduce across the 16 col-lanes) ---
    float mrow[4], lrow[4];
    #pragma unroll
    for (int r = 0; r < 4; ++r) mrow[r] = -INFINITY;
    #pragma unroll
    for (int jt = 0; jt < 16; ++jt) if (jt < jtiles) {
        #pragma unroll
        for (int r = 0; r < 4; ++r) mrow[r] = fmaxf(mrow[r], S[jt][r]);
    }
    #pragma unroll
    for (int r = 0; r < 4; ++r) {
        #pragma unroll
        for (int off = 1; off < 16; off <<= 1)
            mrow[r] = fmaxf(mrow[r], __shfl_xor(mrow[r], off));
    }
    #pragma unroll
    for (int r = 0; r < 4; ++r) lrow[r] = 0.f;
    #pragma unroll
    for (int jt = 0; jt < 16; ++jt) if (jt < jtiles) {
        #pragma unroll
        for (int r = 0; r < 4; ++r) {
            float p = __expf(S[jt][r] - mrow[r]);
            S[jt][r] = p;
            lrow[r] += p;
        }
    }
    #pragma unroll
    for (int r = 0; r < 4; ++r) {
        #pragma unroll
        for (int off = 1; off < 16; off <<= 1)
            lrow[r] += __shfl_xor(lrow[r], off);
    }

    // --- O = P V via LDS layout transform (C-layout -> A-layout), 32 j per chunk ---
    f32x4 O[4];
    #pragma unroll
    for (int i = 0; i < 4; ++i) O[i] = (f32x4){0.f, 0.f, 0.f, 0.f};

    #pragma unroll
    for (int jc = 0; jc < 8; ++jc) {
        if (jc * 2 < jtiles) {
            u16* Pw = &Psm[w][jc & 1][0];
            #pragma unroll
            for (int s2 = 0; s2 < 2; ++s2) {
                const int jt = jc * 2 + s2;
                #pragma unroll
                for (int r = 0; r < 4; ++r) {
                    u16 pv = 0;
                    if (jt < jtiles) pv = f2bf_rne(S[jt][r]);
                    Pw[(quad * 4 + r) * 40 + s2 * 16 + cl] = pv;
                }
            }
            __builtin_amdgcn_s_waitcnt(0xc07f);      // lgkmcnt(0): P writes -> reads
            bf16x8 pf = *(const bf16x8*)&Pw[cl * 40 + quad * 8];
            #pragma unroll
            for (int dt = 0; dt < 4; ++dt) {
                bf16x8 vf = *(const bf16x8*)&Vsm[(dt * 16 + cl) * 264 + jc * 32 + quad * 8];
                O[dt] = __builtin_amdgcn_mfma_f32_16x16x32_bf16(pf, vf, O[dt], 0, 0, 0);
            }
        }
    }

    // --- normalize + store (C layout: row = quad*4+r, col = dt*16+cl) ---
    float inv[4];
    #pragma unroll
    for (int r = 0; r < 4; ++r) inv[r] = 1.0f / lrow[r];
    #pragma unroll
    for (int dt = 0; dt < 4; ++dt)
        #pragma unroll
        for (int r = 0; r < 4; ++r)
            y[gb + (size_t)(qrow + quad * 4 + r) * 1024 + dt * 16 + cl] = O[dt][r] * inv[r];
}

extern "C" void kernel_launch(void* const* d_in, const int* in_sizes, int n_in,
                              void* d_out, int out_size, void* d_ws, size_t ws_size,
                              hipStream_t stream) {
    (void)in_sizes; (void)n_in; (void)out_size; (void)ws_size;
    const float* x  = (const float*)d_in[0];
    const float* Wq = (const float*)d_in[1];
    const float* Wk = (const float*)d_in[2];
    const float* Wv = (const float*)d_in[3];
    const float* Wp = (const float*)d_in[4];
    const float* bp = (const float*)d_in[5];
    float* out = (float*)d_out;
    char* ws = (char*)d_ws;

    u16*    w8   = (u16*)(ws + W8_OFF);
    u16*    xq8  = (u16*)(ws + XQ8_OFF);
    float*  rsx  = (float*)(ws + RSX_OFF);
    float*  rsy  = (float*)(ws + RSY_OFF);
    double* wsum = (double*)(ws + WSUM_OFF);
    double* wpart= (double*)(ws + WPART_OFF);
    u16*    qb   = (u16*)(ws + QB_OFF);
    u16*    kb   = (u16*)(ws + KB_OFF);
    u16*    vb   = (u16*)(ws + VB_OFF);

    wsum1_kernel<<<256, 256, 0, stream>>>(Wq, Wk, Wv, Wp, wpart);
    wsum2_kernel<<<1, 256, 0, stream>>>(wpart, wsum);
    wquant_kernel<<<4096, 256, 0, stream>>>(Wq, Wk, Wv, Wp, wsum, w8);
    actquant_kernel<<<M, 256, 0, stream>>>(x, xq8, rsx);

    dim3 gg(1024 / 128, M / 128);
    // q gets 1/sqrt(hd)=0.125 folded into its dequant scale (exact pow2)
    gemm_kernel<true ><<<gg, 256, 0, stream>>>(xq8, w8 + 0 * 1048576, rsx, wsum + 0, qb, nullptr, 0.125f);
    gemm_kernel<true ><<<gg, 256, 0, stream>>>(xq8, w8 + 1 * 1048576, rsx, wsum + 1, kb, nullptr, 1.0f);
    gemm_kernel<true ><<<gg, 256, 0, stream>>>(xq8, w8 + 2 * 1048576, rsx, wsum + 2, vb, nullptr, 1.0f);

    attn_kernel<<<4 * 1024, 256, 0, stream>>>(qb, kb, vb, out);   // y -> d_out (scratch)

    actquant_kernel<<<M, 256, 0, stream>>>(out, xq8, rsy);        // y -> yq8 (reuse xq8)
    gemm_kernel<false><<<gg, 256, 0, stream>>>(xq8, w8 + 3 * 1048576, rsy, wsum + 3, out, bp, 1.0f);
}

// Round 3
// 341.027 us; speedup vs baseline: 2.5079x; 1.3661x over previous
//
#include <hip/hip_runtime.h>
#include <math.h>

#define AS1 __attribute__((address_space(1)))
#define AS3 __attribute__((address_space(3)))

typedef unsigned short u16;
typedef signed char i8;
typedef short bf16x8 __attribute__((ext_vector_type(8)));
typedef float f32x4 __attribute__((ext_vector_type(4)));
typedef int i32x4 __attribute__((ext_vector_type(4)));

static constexpr int BB = 64, T = 256, C = 1024, H = 16, HD = 64;
static constexpr int M = BB * T;          // 16384 token rows
static constexpr float EPSF = 1e-5f;

// ---- workspace layout (bytes) ----
static constexpr size_t W8_OFF   = 0;                    // 4 x 1M i8 = 4 MiB ternary weights
static constexpr size_t XQ8_OFF  = 4ull  << 20;          // 16M i8 = 16 MiB (reused for yq)
static constexpr size_t RSX_OFF  = 20ull << 20;          // 16384 f32
static constexpr size_t RSY_OFF  = (20ull << 20) + (64 << 10);
static constexpr size_t WSUM_OFF = (20ull << 20) + (128 << 10);   // 4 f64
static constexpr size_t WPART_OFF= WSUM_OFF + 64;                 // 256 f64
static constexpr size_t QB_OFF   = 21ull << 20;          // 32 MiB bf16
static constexpr size_t KB_OFF   = 53ull << 20;          // 32 MiB bf16
static constexpr size_t VB_OFF   = 85ull << 20;          // 32 MiB bf16 (total 117 MiB)

// round-to-nearest-even f32 -> bf16 bits (finite inputs)
__device__ __forceinline__ u16 f2bf_rne(float f) {
    unsigned x = __float_as_uint(f);
    unsigned r = x + 0x7FFF + ((x >> 16) & 1);
    return (u16)(r >> 16);
}

// ---------------- weight |w| sum, stage 1 (deterministic, f64) ----------------
__global__ __launch_bounds__(256) void wsum1_kernel(const float* __restrict__ Wq,
    const float* __restrict__ Wk, const float* __restrict__ Wv,
    const float* __restrict__ Wp, double* __restrict__ wpart)
{
    const int mat = blockIdx.x >> 6;
    const float* W = (mat == 0) ? Wq : (mat == 1) ? Wk : (mat == 2) ? Wv : Wp;
    const int t = threadIdx.x;
    const int base = (blockIdx.x & 63) * 256 + t;
    double s = 0.0;
    for (int i = 0; i < 64; ++i) s += (double)fabsf(W[base + (i << 14)]);
    #pragma unroll
    for (int off = 32; off >= 1; off >>= 1) s += __shfl_down(s, off);
    __shared__ double red[4];
    if ((t & 63) == 0) red[t >> 6] = s;
    __syncthreads();
    if (t == 0) wpart[blockIdx.x] = red[0] + red[1] + red[2] + red[3];
}

__global__ __launch_bounds__(256) void wsum2_kernel(const double* __restrict__ wpart,
                                                    double* __restrict__ wsum)
{
    const int t = threadIdx.x;
    double s = wpart[t];
    #pragma unroll
    for (int off = 32; off >= 1; off >>= 1) s += __shfl_down(s, off);
    if ((t & 63) == 0) wsum[t >> 6] = s;
}

// ---------------- ternary weight quantization -> int8 ----------------
__global__ __launch_bounds__(256) void wquant_kernel(const float* __restrict__ Wq,
    const float* __restrict__ Wk, const float* __restrict__ Wv,
    const float* __restrict__ Wp, const double* __restrict__ wsum,
    i8* __restrict__ w8)
{
    const int mat = blockIdx.x >> 10;
    const float* W = (mat == 0) ? Wq : (mat == 1) ? Wk : (mat == 2) ? Wv : Wp;
    const float mean = (float)(wsum[mat] * (1.0 / 1048576.0));
    const float s = 1.0f / fmaxf(mean, EPSF);
    const int idx = (blockIdx.x & 1023) * 256 + threadIdx.x;   // float4 / char4 index
    float4 w = ((const float4*)W)[idx];
    char4 o;
    o.x = (i8)(int)fminf(fmaxf(rintf(w.x * s), -1.f), 1.f);
    o.y = (i8)(int)fminf(fmaxf(rintf(w.y * s), -1.f), 1.f);
    o.z = (i8)(int)fminf(fmaxf(rintf(w.z * s), -1.f), 1.f);
    o.w = (i8)(int)fminf(fmaxf(rintf(w.w * s), -1.f), 1.f);
    ((char4*)(w8 + (size_t)mat * 1048576))[idx] = o;
}

// ---------------- per-token activation quantization -> int8 ----------------
__global__ __launch_bounds__(256) void actquant_kernel(const float* __restrict__ x,
    i8* __restrict__ xq, float* __restrict__ rs)
{
    const int row = blockIdx.x;
    const int t = threadIdx.x;
    float4 v = ((const float4*)(x + (size_t)row * C))[t];
    float m = fmaxf(fmaxf(fabsf(v.x), fabsf(v.y)), fmaxf(fabsf(v.z), fabsf(v.w)));
    #pragma unroll
    for (int off = 32; off >= 1; off >>= 1) m = fmaxf(m, __shfl_down(m, off));
    __shared__ float red[4];
    if ((t & 63) == 0) red[t >> 6] = m;
    __syncthreads();
    float mm = fmaxf(fmaxf(red[0], red[1]), fmaxf(red[2], red[3]));
    mm = fmaxf(mm, EPSF);
    const float s = 127.0f / mm;
    if (t == 0) rs[row] = mm / 127.0f;
    char4 o;
    o.x = (i8)(int)fminf(fmaxf(rintf(v.x * s), -128.f), 127.f);
    o.y = (i8)(int)fminf(fmaxf(rintf(v.y * s), -128.f), 127.f);
    o.z = (i8)(int)fminf(fmaxf(rintf(v.z * s), -128.f), 127.f);
    o.w = (i8)(int)fminf(fmaxf(rintf(v.w * s), -128.f), 127.f);
    ((char4*)(xq + (size_t)row * C))[t] = o;
}

// ---------------- int8 MFMA GEMM: out[M,1024] = A[M,1024] x W[1024,1024]^T ----------------
// Exact i32 accumulation via mfma_i32_16x16x64_i8 (2x bf16 rate, half staging bytes).
// LDS tile XOR-swizzled: slot (row,kc) holds global chunk (row, kc ^ ((row>>1)&3));
// frag read uses swq = quad ^ ((mr>>1)&3) -> 2-way banks (free) instead of 8-way.
// QKV mode: grid.x = 3 mats x 8 n-blocks, writes dequantized bf16 to q/k/v
// (q gets 1/sqrt(64) folded in). PROJ mode: writes f32 + bias to out.
template<bool QKV>
__global__ __launch_bounds__(256) void gemm_kernel(const i8* __restrict__ A,
    const i8* __restrict__ w8, const float* __restrict__ rs_row,
    const double* __restrict__ wsum, u16* __restrict__ qb, u16* __restrict__ kb,
    u16* __restrict__ vb, float* __restrict__ outp, const float* __restrict__ bias)
{
    constexpr int K = 1024, N = 1024;
    __shared__ __align__(16) i8 Asm[128 * 64];
    __shared__ __align__(16) i8 Bsm[128 * 64];

    const int t = threadIdx.x;
    const int m0 = blockIdx.y * 128;
    const int nb  = QKV ? (int)(blockIdx.x & 7) : (int)blockIdx.x;
    const int mat = QKV ? (int)(blockIdx.x >> 3) : 3;
    const int n0 = nb * 128;
    const i8* Bw = w8 + (size_t)mat * 1048576;

    const int lane = t & 63, wave = t >> 6;
    const int wm = wave >> 1, wn = wave & 1;      // 2x2 wave grid, 64x64 each
    const int mr = lane & 15, quad = lane >> 4;

    i32x4 acc[4][4];
    #pragma unroll
    for (int i = 0; i < 4; ++i)
        #pragma unroll
        for (int j = 0; j < 4; ++j) acc[i][j] = (i32x4){0, 0, 0, 0};

    // staging: 512 slots of 16B per tile; slot c -> row c>>2, k-chunk swizzled
    const int c0 = t, c1 = t + 256;
    const int r0 = c0 >> 2, g0 = ((c0 & 3) ^ ((r0 >> 1) & 3)) * 16;
    const int r1 = c1 >> 2, g1 = ((c1 & 3) ^ ((r1 >> 1) & 3)) * 16;
    const i8* a0 = A  + (size_t)(m0 + r0) * K + g0;
    const i8* a1 = A  + (size_t)(m0 + r1) * K + g1;
    const i8* b0 = Bw + (size_t)(n0 + r0) * K + g0;
    const i8* b1 = Bw + (size_t)(n0 + r1) * K + g1;

    const int swq = (quad ^ ((mr >> 1) & 3)) * 16;   // swizzled k-chunk byte offset

    for (int k0 = 0; k0 < K; k0 += 64) {
        __builtin_amdgcn_global_load_lds((const AS1 void*)(a0 + k0), (AS3 void*)&Asm[c0 * 16], 16, 0, 0);
        __builtin_amdgcn_global_load_lds((const AS1 void*)(a1 + k0), (AS3 void*)&Asm[c1 * 16], 16, 0, 0);
        __builtin_amdgcn_global_load_lds((const AS1 void*)(b0 + k0), (AS3 void*)&Bsm[c0 * 16], 16, 0, 0);
        __builtin_amdgcn_global_load_lds((const AS1 void*)(b1 + k0), (AS3 void*)&Bsm[c1 * 16], 16, 0, 0);
        __syncthreads();
        i32x4 af[4], bf[4];
        #pragma unroll
        for (int i = 0; i < 4; ++i)
            af[i] = *(const i32x4*)&Asm[(wm * 64 + i * 16 + mr) * 64 + swq];
        #pragma unroll
        for (int j = 0; j < 4; ++j)
            bf[j] = *(const i32x4*)&Bsm[(wn * 64 + j * 16 + mr) * 64 + swq];
        #pragma unroll
        for (int i = 0; i < 4; ++i)
            #pragma unroll
            for (int j = 0; j < 4; ++j)
                acc[i][j] = __builtin_amdgcn_mfma_i32_16x16x64_i8(af[i], bf[j], acc[i][j], 0, 0, 0);
        __syncthreads();
    }

    float wsc = fmaxf((float)(wsum[mat] * (1.0 / 1048576.0)), EPSF);
    if (QKV && mat == 0) wsc *= 0.125f;              // fold 1/sqrt(hd) into q scale
    u16* ob = QKV ? ((mat == 0) ? qb : (mat == 1) ? kb : vb) : nullptr;

    #pragma unroll
    for (int i = 0; i < 4; ++i) {
        const int gr0 = m0 + wm * 64 + i * 16 + quad * 4;
        #pragma unroll
        for (int r = 0; r < 4; ++r) {
            const int grow = gr0 + r;
            const float sc = rs_row[grow] * wsc;
            #pragma unroll
            for (int j = 0; j < 4; ++j) {
                const int gcol = n0 + wn * 64 + j * 16 + mr;
                const float vv = (float)acc[i][j][r] * sc;
                if (QKV) {
                    ob[(size_t)grow * N + gcol] = f2bf_rne(vv);
                } else {
                    outp[(size_t)grow * N + gcol] = vv + bias[gcol];
                }
            }
        }
    }
}

// ---------------- MFMA flash attention (unchanged from round 2) ----------------
__global__ __launch_bounds__(256) void attn_kernel(const u16* __restrict__ qb,
    const u16* __restrict__ kb, const u16* __restrict__ vb, float* __restrict__ y)
{
    __shared__ __align__(16) u16 Vsm[64 * 264];      // V^T [d][j], stride 264 (pad 8)
    __shared__ __align__(16) u16 Psm[4][2][16 * 40]; // per-wave P chunk, dbuf, stride 40

    const int t = threadIdx.x;
    const int qt = 3 - (int)(blockIdx.x >> 10);      // heavy qtiles dispatch first
    const int bh = blockIdx.x & 1023;
    const int b = bh >> 4, h = bh & 15;
    const int w = t >> 6, lane = t & 63;
    const int cl = lane & 15, quad = lane >> 4;
    const size_t gb = (size_t)(b * T) * 1024 + h * 64;

    const int jn = (qt + 1) * 64;                    // K/V rows this block needs

    {
        const int j_in = t & 63;
        const int d0 = (t >> 6) * 16;
        for (int jg = 0; jg < jn; jg += 64) {
            const u16* vr = vb + gb + (size_t)(jg + j_in) * 1024 + d0;
            bf16x8 v0 = *(const bf16x8*)vr;
            bf16x8 v1 = *(const bf16x8*)(vr + 8);
            #pragma unroll
            for (int i = 0; i < 8; ++i) {
                Vsm[(d0 + i) * 264 + jg + j_in]     = (u16)v0[i];
                Vsm[(d0 + 8 + i) * 264 + jg + j_in] = (u16)v1[i];
            }
        }
    }
    __syncthreads();

    const int qrow = qt * 64 + w * 16;
    const int jtiles = (qrow >> 4) + 1;

    const u16* qrp = qb + gb + (size_t)(qrow + cl) * 1024 + quad * 8;
    bf16x8 qf0 = *(const bf16x8*)qrp;
    bf16x8 qf1 = *(const bf16x8*)(qrp + 32);

    f32x4 S[16];
    #pragma unroll
    for (int i = 0; i < 16; ++i) S[i] = (f32x4){0.f, 0.f, 0.f, 0.f};

    const u16* krp = kb + gb + (size_t)cl * 1024 + quad * 8;
    #pragma unroll
    for (int jt = 0; jt < 16; ++jt) {
        if (jt < jtiles) {
            const u16* kp = krp + (size_t)(jt * 16) * 1024;
            bf16x8 kf0 = *(const bf16x8*)kp;
            bf16x8 kf1 = *(const bf16x8*)(kp + 32);
            S[jt] = __builtin_amdgcn_mfma_f32_16x16x32_bf16(qf0, kf0, S[jt], 0, 0, 0);
            S[jt] = __builtin_amdgcn_mfma_f32_16x16x32_bf16(qf1, kf1, S[jt], 0, 0, 0);
            if (jt == jtiles - 1) {
                #pragma unroll
                for (int r = 0; r < 4; ++r)
                    if (cl > quad * 4 + r) S[jt][r] = -INFINITY;
            }
        }
    }

    float mrow[4], lrow[4];
    #pragma unroll
    for (int r = 0; r < 4; ++r) mrow[r] = -INFINITY;
    #pragma unroll
    for (int jt = 0; jt < 16; ++jt) if (jt < jtiles) {
        #pragma unroll
        for (int r = 0; r < 4; ++r) mrow[r] = fmaxf(mrow[r], S[jt][r]);
    }
    #pragma unroll
    for (int r = 0; r < 4; ++r) {
        #pragma unroll
        for (int off = 1; off < 16; off <<= 1)
            mrow[r] = fmaxf(mrow[r], __shfl_xor(mrow[r], off));
    }
    #pragma unroll
    for (int r = 0; r < 4; ++r) lrow[r] = 0.f;
    #pragma unroll
    for (int jt = 0; jt < 16; ++jt) if (jt < jtiles) {
        #pragma unroll
        for (int r = 0; r < 4; ++r) {
            float p = __expf(S[jt][r] - mrow[r]);
            S[jt][r] = p;
            lrow[r] += p;
        }
    }
    #pragma unroll
    for (int r = 0; r < 4; ++r) {
        #pragma unroll
        for (int off = 1; off < 16; off <<= 1)
            lrow[r] += __shfl_xor(lrow[r], off);
    }

    f32x4 O[4];
    #pragma unroll
    for (int i = 0; i < 4; ++i) O[i] = (f32x4){0.f, 0.f, 0.f, 0.f};

    #pragma unroll
    for (int jc = 0; jc < 8; ++jc) {
        if (jc * 2 < jtiles) {
            u16* Pw = &Psm[w][jc & 1][0];
            #pragma unroll
            for (int s2 = 0; s2 < 2; ++s2) {
                const int jt = jc * 2 + s2;
                #pragma unroll
                for (int r = 0; r < 4; ++r) {
                    u16 pv = 0;
                    if (jt < jtiles) pv = f2bf_rne(S[jt][r]);
                    Pw[(quad * 4 + r) * 40 + s2 * 16 + cl] = pv;
                }
            }
            __builtin_amdgcn_s_waitcnt(0xc07f);      // lgkmcnt(0)
            bf16x8 pf = *(const bf16x8*)&Pw[cl * 40 + quad * 8];
            #pragma unroll
            for (int dt = 0; dt < 4; ++dt) {
                bf16x8 vf = *(const bf16x8*)&Vsm[(dt * 16 + cl) * 264 + jc * 32 + quad * 8];
                O[dt] = __builtin_amdgcn_mfma_f32_16x16x32_bf16(pf, vf, O[dt], 0, 0, 0);
            }
        }
    }

    float inv[4];
    #pragma unroll
    for (int r = 0; r < 4; ++r) inv[r] = 1.0f / lrow[r];
    #pragma unroll
    for (int dt = 0; dt < 4; ++dt)
        #pragma unroll
        for (int r = 0; r < 4; ++r)
            y[gb + (size_t)(qrow + quad * 4 + r) * 1024 + dt * 16 + cl] = O[dt][r] * inv[r];
}

extern "C" void kernel_launch(void* const* d_in, const int* in_sizes, int n_in,
                              void* d_out, int out_size, void* d_ws, size_t ws_size,
                              hipStream_t stream) {
    (void)in_sizes; (void)n_in; (void)out_size; (void)ws_size;
    const float* x  = (const float*)d_in[0];
    const float* Wq = (const float*)d_in[1];
    const float* Wk = (const float*)d_in[2];
    const float* Wv = (const float*)d_in[3];
    const float* Wp = (const float*)d_in[4];
    const float* bp = (const float*)d_in[5];
    float* out = (float*)d_out;
    char* ws = (char*)d_ws;

    i8*     w8   = (i8*)(ws + W8_OFF);
    i8*     xq8  = (i8*)(ws + XQ8_OFF);
    float*  rsx  = (float*)(ws + RSX_OFF);
    float*  rsy  = (float*)(ws + RSY_OFF);
    double* wsum = (double*)(ws + WSUM_OFF);
    double* wpart= (double*)(ws + WPART_OFF);
    u16*    qb   = (u16*)(ws + QB_OFF);
    u16*    kb   = (u16*)(ws + KB_OFF);
    u16*    vb   = (u16*)(ws + VB_OFF);

    wsum1_kernel<<<256, 256, 0, stream>>>(Wq, Wk, Wv, Wp, wpart);
    wsum2_kernel<<<1, 256, 0, stream>>>(wpart, wsum);
    wquant_kernel<<<4096, 256, 0, stream>>>(Wq, Wk, Wv, Wp, wsum, w8);
    actquant_kernel<<<M, 256, 0, stream>>>(x, xq8, rsx);

    // fused q/k/v: 3 mats x 8 n-blocks in x, 128 m-blocks in y
    gemm_kernel<true ><<<dim3(24, 128), 256, 0, stream>>>(xq8, w8, rsx, wsum, qb, kb, vb, nullptr, nullptr);

    attn_kernel<<<4 * 1024, 256, 0, stream>>>(qb, kb, vb, out);   // y -> d_out (scratch)

    actquant_kernel<<<M, 256, 0, stream>>>(out, xq8, rsy);        // y -> yq8
    gemm_kernel<false><<<dim3(8, 128), 256, 0, stream>>>(xq8, w8, rsy, wsum, nullptr, nullptr, nullptr, out, bp);
}

// Round 4
// 336.642 us; speedup vs baseline: 2.5405x; 1.0130x over previous
//
#include <hip/hip_runtime.h>
#include <math.h>

#define AS1 __attribute__((address_space(1)))
#define AS3 __attribute__((address_space(3)))

typedef unsigned short u16;
typedef signed char i8;
typedef short bf16x8 __attribute__((ext_vector_type(8)));
typedef float f32x4 __attribute__((ext_vector_type(4)));
typedef int i32x4 __attribute__((ext_vector_type(4)));

static constexpr int BB = 64, T = 256, C = 1024, H = 16, HD = 64;
static constexpr int M = BB * T;          // 16384 token rows
static constexpr float EPSF = 1e-5f;

// ---- workspace layout (bytes) ----
static constexpr size_t W8_OFF   = 0;                    // 4 x 1M i8 = 4 MiB ternary weights
static constexpr size_t XQ8_OFF  = 4ull  << 20;          // 16M i8 = 16 MiB (reused for yq)
static constexpr size_t RSX_OFF  = 20ull << 20;          // 16384 f32
static constexpr size_t RSY_OFF  = (20ull << 20) + (64 << 10);
static constexpr size_t WSUM_OFF = (20ull << 20) + (128 << 10);   // 4 f64
static constexpr size_t WPART_OFF= WSUM_OFF + 64;                 // 256 f64
static constexpr size_t QB_OFF   = 21ull << 20;          // 32 MiB bf16
static constexpr size_t KB_OFF   = 53ull << 20;          // 32 MiB bf16
static constexpr size_t VT_OFF   = 85ull << 20;          // 32 MiB bf16 V^T [b][h*64+d][tloc]

// round-to-nearest-even f32 -> bf16 bits (finite inputs)
__device__ __forceinline__ u16 f2bf_rne(float f) {
    unsigned x = __float_as_uint(f);
    unsigned r = x + 0x7FFF + ((x >> 16) & 1);
    return (u16)(r >> 16);
}

// ---------------- weight |w| sum, stage 1 (deterministic, f64) ----------------
__global__ __launch_bounds__(256) void wsum1_kernel(const float* __restrict__ Wq,
    const float* __restrict__ Wk, const float* __restrict__ Wv,
    const float* __restrict__ Wp, double* __restrict__ wpart)
{
    const int mat = blockIdx.x >> 6;
    const float* W = (mat == 0) ? Wq : (mat == 1) ? Wk : (mat == 2) ? Wv : Wp;
    const int t = threadIdx.x;
    const int base = (blockIdx.x & 63) * 256 + t;
    double s = 0.0;
    for (int i = 0; i < 64; ++i) s += (double)fabsf(W[base + (i << 14)]);
    #pragma unroll
    for (int off = 32; off >= 1; off >>= 1) s += __shfl_down(s, off);
    __shared__ double red[4];
    if ((t & 63) == 0) red[t >> 6] = s;
    __syncthreads();
    if (t == 0) wpart[blockIdx.x] = red[0] + red[1] + red[2] + red[3];
}

__global__ __launch_bounds__(256) void wsum2_kernel(const double* __restrict__ wpart,
                                                    double* __restrict__ wsum)
{
    const int t = threadIdx.x;
    double s = wpart[t];
    #pragma unroll
    for (int off = 32; off >= 1; off >>= 1) s += __shfl_down(s, off);
    if ((t & 63) == 0) wsum[t >> 6] = s;
}

// ---------------- ternary weight quantization -> int8 ----------------
__global__ __launch_bounds__(256) void wquant_kernel(const float* __restrict__ Wq,
    const float* __restrict__ Wk, const float* __restrict__ Wv,
    const float* __restrict__ Wp, const double* __restrict__ wsum,
    i8* __restrict__ w8)
{
    const int mat = blockIdx.x >> 10;
    const float* W = (mat == 0) ? Wq : (mat == 1) ? Wk : (mat == 2) ? Wv : Wp;
    const float mean = (float)(wsum[mat] * (1.0 / 1048576.0));
    const float s = 1.0f / fmaxf(mean, EPSF);
    const int idx = (blockIdx.x & 1023) * 256 + threadIdx.x;   // float4 / char4 index
    float4 w = ((const float4*)W)[idx];
    char4 o;
    o.x = (i8)(int)fminf(fmaxf(rintf(w.x * s), -1.f), 1.f);
    o.y = (i8)(int)fminf(fmaxf(rintf(w.y * s), -1.f), 1.f);
    o.z = (i8)(int)fminf(fmaxf(rintf(w.z * s), -1.f), 1.f);
    o.w = (i8)(int)fminf(fmaxf(rintf(w.w * s), -1.f), 1.f);
    ((char4*)(w8 + (size_t)mat * 1048576))[idx] = o;
}

// ---------------- per-token activation quantization -> int8 ----------------
__global__ __launch_bounds__(256) void actquant_kernel(const float* __restrict__ x,
    i8* __restrict__ xq, float* __restrict__ rs)
{
    const int row = blockIdx.x;
    const int t = threadIdx.x;
    float4 v = ((const float4*)(x + (size_t)row * C))[t];
    float m = fmaxf(fmaxf(fabsf(v.x), fabsf(v.y)), fmaxf(fabsf(v.z), fabsf(v.w)));
    #pragma unroll
    for (int off = 32; off >= 1; off >>= 1) m = fmaxf(m, __shfl_down(m, off));
    __shared__ float red[4];
    if ((t & 63) == 0) red[t >> 6] = m;
    __syncthreads();
    float mm = fmaxf(fmaxf(red[0], red[1]), fmaxf(red[2], red[3]));
    mm = fmaxf(mm, EPSF);
    const float s = 127.0f / mm;
    if (t == 0) rs[row] = mm / 127.0f;
    char4 o;
    o.x = (i8)(int)fminf(fmaxf(rintf(v.x * s), -128.f), 127.f);
    o.y = (i8)(int)fminf(fmaxf(rintf(v.y * s), -128.f), 127.f);
    o.z = (i8)(int)fminf(fmaxf(rintf(v.z * s), -128.f), 127.f);
    o.w = (i8)(int)fminf(fmaxf(rintf(v.w * s), -128.f), 127.f);
    ((char4*)(xq + (size_t)row * C))[t] = o;
}

// ---------------- int8 MFMA GEMM: out[M,1024] = A[M,1024] x W[1024,1024]^T ----------------
// Exact i32 accumulation via mfma_i32_16x16x64_i8. LDS tile XOR-swizzled (2-way banks).
// QKV mode: mats 0/1 (q,k) write row-major bf16; mat 2 (v) writes V^T [b][c][tloc]
// for attention's direct B-fragment loads. PROJ mode: f32 + bias.
template<bool QKV>
__global__ __launch_bounds__(256) void gemm_kernel(const i8* __restrict__ A,
    const i8* __restrict__ w8, const float* __restrict__ rs_row,
    const double* __restrict__ wsum, u16* __restrict__ qb, u16* __restrict__ kb,
    u16* __restrict__ vt, float* __restrict__ outp, const float* __restrict__ bias)
{
    constexpr int K = 1024, N = 1024;
    __shared__ __align__(16) i8 Asm[128 * 64];
    __shared__ __align__(16) i8 Bsm[128 * 64];

    const int t = threadIdx.x;
    const int m0 = blockIdx.y * 128;
    const int nb  = QKV ? (int)(blockIdx.x & 7) : (int)blockIdx.x;
    const int mat = QKV ? (int)(blockIdx.x >> 3) : 3;
    const int n0 = nb * 128;
    const i8* Bw = w8 + (size_t)mat * 1048576;

    const int lane = t & 63, wave = t >> 6;
    const int wm = wave >> 1, wn = wave & 1;      // 2x2 wave grid, 64x64 each
    const int mr = lane & 15, quad = lane >> 4;

    i32x4 acc[4][4];
    #pragma unroll
    for (int i = 0; i < 4; ++i)
        #pragma unroll
        for (int j = 0; j < 4; ++j) acc[i][j] = (i32x4){0, 0, 0, 0};

    const int c0 = t, c1 = t + 256;
    const int r0 = c0 >> 2, g0 = ((c0 & 3) ^ ((r0 >> 1) & 3)) * 16;
    const int r1 = c1 >> 2, g1 = ((c1 & 3) ^ ((r1 >> 1) & 3)) * 16;
    const i8* a0 = A  + (size_t)(m0 + r0) * K + g0;
    const i8* a1 = A  + (size_t)(m0 + r1) * K + g1;
    const i8* b0 = Bw + (size_t)(n0 + r0) * K + g0;
    const i8* b1 = Bw + (size_t)(n0 + r1) * K + g1;

    const int swq = (quad ^ ((mr >> 1) & 3)) * 16;   // swizzled k-chunk byte offset

    for (int k0 = 0; k0 < K; k0 += 64) {
        __builtin_amdgcn_global_load_lds((const AS1 void*)(a0 + k0), (AS3 void*)&Asm[c0 * 16], 16, 0, 0);
        __builtin_amdgcn_global_load_lds((const AS1 void*)(a1 + k0), (AS3 void*)&Asm[c1 * 16], 16, 0, 0);
        __builtin_amdgcn_global_load_lds((const AS1 void*)(b0 + k0), (AS3 void*)&Bsm[c0 * 16], 16, 0, 0);
        __builtin_amdgcn_global_load_lds((const AS1 void*)(b1 + k0), (AS3 void*)&Bsm[c1 * 16], 16, 0, 0);
        __syncthreads();
        i32x4 af[4], bf[4];
        #pragma unroll
        for (int i = 0; i < 4; ++i)
            af[i] = *(const i32x4*)&Asm[(wm * 64 + i * 16 + mr) * 64 + swq];
        #pragma unroll
        for (int j = 0; j < 4; ++j)
            bf[j] = *(const i32x4*)&Bsm[(wn * 64 + j * 16 + mr) * 64 + swq];
        #pragma unroll
        for (int i = 0; i < 4; ++i)
            #pragma unroll
            for (int j = 0; j < 4; ++j)
                acc[i][j] = __builtin_amdgcn_mfma_i32_16x16x64_i8(af[i], bf[j], acc[i][j], 0, 0, 0);
        __syncthreads();
    }

    float wsc = fmaxf((float)(wsum[mat] * (1.0 / 1048576.0)), EPSF);
    if (QKV && mat == 0) wsc *= 0.125f;              // fold 1/sqrt(hd) into q scale

    if (QKV && mat == 2) {
        // V^T store: vt[(b*1024 + col)*256 + tloc], 4 consecutive tokens per ushort4
        #pragma unroll
        for (int i = 0; i < 4; ++i) {
            const int gr0 = m0 + wm * 64 + i * 16 + quad * 4;
            const int bb = gr0 >> 8, tl = gr0 & 255;
            const float4 rs4 = *(const float4*)(rs_row + gr0);
            #pragma unroll
            for (int j = 0; j < 4; ++j) {
                const int gcol = n0 + wn * 64 + j * 16 + mr;
                ushort4 o;
                o.x = f2bf_rne((float)acc[i][j][0] * rs4.x * wsc);
                o.y = f2bf_rne((float)acc[i][j][1] * rs4.y * wsc);
                o.z = f2bf_rne((float)acc[i][j][2] * rs4.z * wsc);
                o.w = f2bf_rne((float)acc[i][j][3] * rs4.w * wsc);
                *(ushort4*)(vt + (size_t)(bb * 1024 + gcol) * 256 + tl) = o;
            }
        }
        return;
    }

    u16* ob = QKV ? ((mat == 0) ? qb : kb) : nullptr;
    #pragma unroll
    for (int i = 0; i < 4; ++i) {
        const int gr0 = m0 + wm * 64 + i * 16 + quad * 4;
        #pragma unroll
        for (int r = 0; r < 4; ++r) {
            const int grow = gr0 + r;
            const float sc = rs_row[grow] * wsc;
            #pragma unroll
            for (int j = 0; j < 4; ++j) {
                const int gcol = n0 + wn * 64 + j * 16 + mr;
                const float vv = (float)acc[i][j][r] * sc;
                if (QKV) {
                    ob[(size_t)grow * N + gcol] = f2bf_rne(vv);
                } else {
                    outp[(size_t)grow * N + gcol] = vv + bias[gcol];
                }
            }
        }
    }
}

// ---------------- LDS-free MFMA flash attention ----------------
// block = (b,h,qtile); wave = 16 q-rows. S^T = K Q^T (C layout: row=j, col=q)
// -> softmax reduces over regs+quads (2 shuffles) -> P^T->A-frag via 8
// ds_bpermute + 4 selects per 32-j chunk -> O = P V with V^T B-frags straight
// from global. No LDS, no barriers; occupancy is VGPR-bound.
__global__ __launch_bounds__(256) void attn_kernel(const u16* __restrict__ qb,
    const u16* __restrict__ kb, const u16* __restrict__ vt, float* __restrict__ y)
{
    const int t = threadIdx.x;
    const int qt = 3 - (int)(blockIdx.x >> 10);      // heavy qtiles dispatch first
    const int bh = blockIdx.x & 1023;
    const int b = bh >> 4, h = bh & 15;
    const int w = t >> 6, lane = t & 63;
    const int cl = lane & 15, quad = lane >> 4;
    const size_t gb = (size_t)(b * T) * 1024 + h * 64;             // q/k row-major base
    const u16* vtb = vt + (size_t)(b * 1024 + h * 64) * 256;       // V^T base

    const int qrow = qt * 64 + w * 16;
    const int jtiles = (qrow >> 4) + 1;              // causal: j-tiles 0..jtiles-1

    const u16* qrp = qb + gb + (size_t)(qrow + cl) * 1024 + quad * 8;
    bf16x8 qf0 = *(const bf16x8*)qrp;                // B-frag: n=q, k=d
    bf16x8 qf1 = *(const bf16x8*)(qrp + 32);

    f32x4 Sp[16];
    #pragma unroll
    for (int i = 0; i < 16; ++i) Sp[i] = (f32x4){0.f, 0.f, 0.f, 0.f};

    // --- S^T = K Q^T: A-frag m=j (lane cl = j-local), k=d ---
    const u16* krp = kb + gb + (size_t)cl * 1024 + quad * 8;
    #pragma unroll
    for (int jt = 0; jt < 16; ++jt) {
        if (jt < jtiles) {
            const u16* kp = krp + (size_t)(jt * 16) * 1024;
            bf16x8 kf0 = *(const bf16x8*)kp;
            bf16x8 kf1 = *(const bf16x8*)(kp + 32);
            Sp[jt] = __builtin_amdgcn_mfma_f32_16x16x32_bf16(kf0, qf0, Sp[jt], 0, 0, 0);
            Sp[jt] = __builtin_amdgcn_mfma_f32_16x16x32_bf16(kf1, qf1, Sp[jt], 0, 0, 0);
            if (jt == jtiles - 1) {                  // diagonal: mask j > q
                #pragma unroll
                for (int r = 0; r < 4; ++r)
                    if (quad * 4 + r > cl) Sp[jt][r] = -INFINITY;
            }
        }
    }

    // --- softmax over j (regs x quads); q = cl is lane-resident ---
    float mx = -INFINITY;
    #pragma unroll
    for (int jt = 0; jt < 16; ++jt) if (jt < jtiles) {
        #pragma unroll
        for (int r = 0; r < 4; ++r) mx = fmaxf(mx, Sp[jt][r]);
    }
    mx = fmaxf(mx, __shfl_xor(mx, 16));
    mx = fmaxf(mx, __shfl_xor(mx, 32));
    float l = 0.f;
    #pragma unroll
    for (int jt = 0; jt < 16; ++jt) if (jt < jtiles) {
        #pragma unroll
        for (int r = 0; r < 4; ++r) {
            float p = __expf(Sp[jt][r] - mx);
            Sp[jt][r] = p;
            l += p;
        }
    }
    l += __shfl_xor(l, 16);
    l += __shfl_xor(l, 32);

    // --- O = P V: A-frag built in-register from P^T via bpermute ---
    f32x4 O[4];
    #pragma unroll
    for (int i = 0; i < 4; ++i) O[i] = (f32x4){0.f, 0.f, 0.f, 0.f};

    const int s01 = ((quad & 1) << 5) + cl;          // src lane for frag slots 0-3
    const bool lo = quad < 2;                        // dest quads 0,1 use tile 2jc
    #pragma unroll
    for (int jc = 0; jc < 8; ++jc) {
        if (jc * 2 < jtiles) {
            int pk[2][2];                            // [tile][reg-pair] bf16x2
            #pragma unroll
            for (int s = 0; s < 2; ++s) {
                const f32x4 v = Sp[jc * 2 + s];      // tile >= jtiles is all-zero
                pk[s][0] = (int)((unsigned)f2bf_rne(v[0]) | ((unsigned)f2bf_rne(v[1]) << 16));
                pk[s][1] = (int)((unsigned)f2bf_rne(v[2]) | ((unsigned)f2bf_rne(v[3]) << 16));
            }
            int a0 = __shfl(pk[0][0], s01),      a1 = __shfl(pk[0][1], s01);
            int a2 = __shfl(pk[0][0], s01 + 16), a3 = __shfl(pk[0][1], s01 + 16);
            int b0 = __shfl(pk[1][0], s01),      b1 = __shfl(pk[1][1], s01);
            int b2 = __shfl(pk[1][0], s01 + 16), b3 = __shfl(pk[1][1], s01 + 16);
            union { int i[4]; bf16x8 v; } af;
            af.i[0] = lo ? a0 : b0;
            af.i[1] = lo ? a1 : b1;
            af.i[2] = lo ? a2 : b2;
            af.i[3] = lo ? a3 : b3;
            const u16* vp = vtb + (size_t)cl * 256 + jc * 32 + quad * 8;
            #pragma unroll
            for (int dt = 0; dt < 4; ++dt) {
                bf16x8 vf = *(const bf16x8*)(vp + (size_t)dt * 16 * 256);
                O[dt] = __builtin_amdgcn_mfma_f32_16x16x32_bf16(af.v, vf, O[dt], 0, 0, 0);
            }
        }
    }

    // --- normalize + store: O row = q-local = quad*4+r, col = d = dt*16+cl ---
    float inv[4];
    #pragma unroll
    for (int r = 0; r < 4; ++r) inv[r] = 1.0f / __shfl(l, quad * 4 + r);
    #pragma unroll
    for (int dt = 0; dt < 4; ++dt)
        #pragma unroll
        for (int r = 0; r < 4; ++r)
            y[gb + (size_t)(qrow + quad * 4 + r) * 1024 + dt * 16 + cl] = O[dt][r] * inv[r];
}

extern "C" void kernel_launch(void* const* d_in, const int* in_sizes, int n_in,
                              void* d_out, int out_size, void* d_ws, size_t ws_size,
                              hipStream_t stream) {
    (void)in_sizes; (void)n_in; (void)out_size; (void)ws_size;
    const float* x  = (const float*)d_in[0];
    const float* Wq = (const float*)d_in[1];
    const float* Wk = (const float*)d_in[2];
    const float* Wv = (const float*)d_in[3];
    const float* Wp = (const float*)d_in[4];
    const float* bp = (const float*)d_in[5];
    float* out = (float*)d_out;
    char* ws = (char*)d_ws;

    i8*     w8   = (i8*)(ws + W8_OFF);
    i8*     xq8  = (i8*)(ws + XQ8_OFF);
    float*  rsx  = (float*)(ws + RSX_OFF);
    float*  rsy  = (float*)(ws + RSY_OFF);
    double* wsum = (double*)(ws + WSUM_OFF);
    double* wpart= (double*)(ws + WPART_OFF);
    u16*    qb   = (u16*)(ws + QB_OFF);
    u16*    kb   = (u16*)(ws + KB_OFF);
    u16*    vt   = (u16*)(ws + VT_OFF);

    wsum1_kernel<<<256, 256, 0, stream>>>(Wq, Wk, Wv, Wp, wpart);
    wsum2_kernel<<<1, 256, 0, stream>>>(wpart, wsum);
    wquant_kernel<<<4096, 256, 0, stream>>>(Wq, Wk, Wv, Wp, wsum, w8);
    actquant_kernel<<<M, 256, 0, stream>>>(x, xq8, rsx);

    // fused q/k/v: 3 mats x 8 n-blocks in x, 128 m-blocks in y
    gemm_kernel<true ><<<dim3(24, 128), 256, 0, stream>>>(xq8, w8, rsx, wsum, qb, kb, vt, nullptr, nullptr);

    attn_kernel<<<4 * 1024, 256, 0, stream>>>(qb, kb, vt, out);   // y -> d_out (scratch)

    actquant_kernel<<<M, 256, 0, stream>>>(out, xq8, rsy);        // y -> yq8
    gemm_kernel<false><<<dim3(8, 128), 256, 0, stream>>>(xq8, w8, rsy, wsum, nullptr, nullptr, nullptr, out, bp);
}